// Round 6
// baseline (10103.650 us; speedup 1.0000x reference)
//
#include <hip/hip_runtime.h>
#include <hip/hip_fp16.h>

// LSTM: B=32, T=4096, D=256, H=256, gates=1024 (i,g,f,o), HORIZON=24
// k_scan v6: IN-LOOP register pins. v5's pin was outside the loop -> RA split the
//   live range and reloaded weights inside the loop anyway (VGPR stuck at 120,
//   ~460KB/step/CU L2 re-stream = the real bottleneck R1-R5). Pinning every
//   iteration makes spilling cost a per-step reload, so RA keeps 22 rows x 8 cols
//   (176 VGPRs) resident. Tail 10 rows stream from L2 via coalesced global loads
//   (WS buffer, VMEM pipe) instead of LDS. One barrier/step, DPP quad-reduce.

#define T_STEPS 4096
#define RROWS 22
#define SROWS 10
#define HBUFW 144      // h-pair buffer: 4 quarters * 36 words (bank-disjoint)

typedef short short8 __attribute__((ext_vector_type(8)));
typedef float f32x4 __attribute__((ext_vector_type(4)));
typedef _Float16 half2_t __attribute__((ext_vector_type(2)));
typedef unsigned int u32x2 __attribute__((ext_vector_type(2)));
typedef unsigned int u32x4 __attribute__((ext_vector_type(4)));

__device__ inline unsigned short f32_to_bf16(float f) {
  unsigned int u = __builtin_bit_cast(unsigned int, f);
  u = u + 0x7fffu + ((u >> 16) & 1u);   // RNE
  return (unsigned short)(u >> 16);
}

__device__ inline float fdot2f(unsigned int w, unsigned int h, float acc) {
  return __builtin_amdgcn_fdot2(__builtin_bit_cast(half2_t, w),
                                __builtin_bit_cast(half2_t, h), acc, false);
}

// ---------------- prep: x f32 -> bf16 ----------------
__global__ void k_prep_x(const float4* __restrict__ x, unsigned short* __restrict__ xbf, int n4) {
  int i = blockIdx.x * blockDim.x + threadIdx.x;
  if (i >= n4) return;
  float4 v = x[i];
  ushort4 o;
  o.x = f32_to_bf16(v.x); o.y = f32_to_bf16(v.y);
  o.z = f32_to_bf16(v.z); o.w = f32_to_bf16(v.w);
  ((ushort4*)xbf)[i] = o;
}

// ---------------- prep: weights ----------------
__global__ void k_prep_w(const float* __restrict__ W, unsigned short* __restrict__ WxT,
                         unsigned int* __restrict__ Whp) {
  int i = blockIdx.x * blockDim.x + threadIdx.x;
  if (i < 256 * 1024) {
    int n = i >> 8, k = i & 255;
    WxT[i] = f32_to_bf16(W[k * 1024 + n]);
  } else {
    int j = i - 256 * 1024;
    int p = j >> 10, c = j & 1023;
    _Float16 lo = (_Float16)W[(256 + 2 * p) * 1024 + c];
    _Float16 hi = (_Float16)W[(257 + 2 * p) * 1024 + c];
    Whp[j] = (unsigned int)__builtin_bit_cast(unsigned short, lo) |
             ((unsigned int)__builtin_bit_cast(unsigned short, hi) << 16);
  }
}

// ---------------- prep: stream-tail buffer (runs AFTER xproj; reuses xbf space) ----
// WS[rr][t][j] = Whp[32*(t&3) + RROWS + rr][ (j>>1)*256 + 2*(t>>2) + (j&1) ]
__global__ void k_prep_ws(const unsigned int* __restrict__ Whp, unsigned int* __restrict__ WS) {
  int i = blockIdx.x * blockDim.x + threadIdx.x;   // < 10*512*8 = 40960
  if (i >= SROWS * 512 * 8) return;
  int rr = i >> 12, rem = i & 4095, t = rem >> 3, j = rem & 7;
  int col = ((j >> 1) << 8) + 2 * (t >> 2) + (j & 1);
  WS[i] = Whp[(size_t)(32 * (t & 3) + RROWS + rr) * 1024 + col];
}

// ---------------- xproj: gates_x = x @ Wx + b (+1 on f-gate) ----------------
__global__ __launch_bounds__(256) void k_xproj(const unsigned short* __restrict__ A,
                                               const unsigned short* __restrict__ BT,
                                               const float* __restrict__ bias,
                                               __half* __restrict__ G) {
  int bm = blockIdx.x * 64;
  int bn = blockIdx.y * 64;
  int lane = threadIdx.x & 63, wave = threadIdx.x >> 6;
  int wm = (wave & 1) * 32, wn = (wave >> 1) * 32;
  int q = lane >> 4, l16 = lane & 15;

  f32x4 acc[2][2] = {};
  const unsigned short* Ab = A + (size_t)(bm + wm + l16) * 256 + q * 8;
  const unsigned short* Bb = BT + (size_t)(bn + wn + l16) * 256 + q * 8;

#pragma unroll
  for (int kk = 0; kk < 8; ++kk) {
    short8 a0 = *(const short8*)(Ab + kk * 32);
    short8 a1 = *(const short8*)(Ab + 16 * 256 + kk * 32);
    short8 b0 = *(const short8*)(Bb + kk * 32);
    short8 b1 = *(const short8*)(Bb + 16 * 256 + kk * 32);
    acc[0][0] = __builtin_amdgcn_mfma_f32_16x16x32_bf16(a0, b0, acc[0][0], 0, 0, 0);
    acc[0][1] = __builtin_amdgcn_mfma_f32_16x16x32_bf16(a0, b1, acc[0][1], 0, 0, 0);
    acc[1][0] = __builtin_amdgcn_mfma_f32_16x16x32_bf16(a1, b0, acc[1][0], 0, 0, 0);
    acc[1][1] = __builtin_amdgcn_mfma_f32_16x16x32_bf16(a1, b1, acc[1][1], 0, 0, 0);
  }

#pragma unroll
  for (int nt = 0; nt < 2; ++nt) {
    int col = bn + wn + nt * 16 + l16;
    float bv = bias[col] + ((col >= 512 && col < 768) ? 1.0f : 0.0f);
#pragma unroll
    for (int mt = 0; mt < 2; ++mt) {
#pragma unroll
      for (int r = 0; r < 4; ++r) {
        int row = bm + wm + mt * 16 + q * 4 + r;
        G[(size_t)row * 1024 + col] = __float2half_rn(acc[mt][nt][r] + bv);
      }
    }
  }
}

// ---------------- recurrent scan v6 ----------------
#define ROWS22(M) M(0) M(1) M(2) M(3) M(4) M(5) M(6) M(7) M(8) M(9) M(10) M(11) \
                  M(12) M(13) M(14) M(15) M(16) M(17) M(18) M(19) M(20) M(21)

#define DEF_ROW(r) u32x4 wa##r, wb##r;

#define LD_ROW(r) { const unsigned int* p = Whp + (size_t)(32 * kq + (r)) * 1024 + c2; \
  u32x2 pi = *(const u32x2*)(p);        u32x2 pg = *(const u32x2*)(p + 256); \
  u32x2 pf = *(const u32x2*)(p + 512);  u32x2 po = *(const u32x2*)(p + 768); \
  wa##r = u32x4{pi.x, pi.y, pg.x, pg.y}; wb##r = u32x4{pf.x, pf.y, po.x, po.y}; }

// IN-LOOP pin: forces the values to occupy VGPRs at every iteration
#define PIN_ROW2(r0, r1) asm volatile("" : "+v"(wa##r0), "+v"(wb##r0), "+v"(wa##r1), "+v"(wb##r1));

#define DOT_ROW(r, hv) \
  acc0 = fdot2f(wa##r.x, (hv), acc0); acc1 = fdot2f(wa##r.y, (hv), acc1); \
  acc2 = fdot2f(wa##r.z, (hv), acc2); acc3 = fdot2f(wa##r.w, (hv), acc3); \
  acc4 = fdot2f(wb##r.x, (hv), acc4); acc5 = fdot2f(wb##r.y, (hv), acc5); \
  acc6 = fdot2f(wb##r.z, (hv), acc6); acc7 = fdot2f(wb##r.w, (hv), acc7);

#define DOT_PAIR(r0, r1) { u32x2 hh = *(const u32x2*)(hr + (r0)); \
  DOT_ROW(r0, hh.x); DOT_ROW(r1, hh.y); }

#define SLOAD(n) u32x4 sa##n = *(const u32x4*)(wsp + (n) * 4096); \
                 u32x4 sb##n = *(const u32x4*)(wsp + (n) * 4096 + 4);
#define SDOT(n, hv) \
  acc0 = fdot2f(sa##n.x, (hv), acc0); acc1 = fdot2f(sa##n.y, (hv), acc1); \
  acc2 = fdot2f(sa##n.z, (hv), acc2); acc3 = fdot2f(sa##n.w, (hv), acc3); \
  acc4 = fdot2f(sb##n.x, (hv), acc4); acc5 = fdot2f(sb##n.y, (hv), acc5); \
  acc6 = fdot2f(sb##n.z, (hv), acc6); acc7 = fdot2f(sb##n.w, (hv), acc7);

__global__
__attribute__((amdgpu_flat_work_group_size(512, 512), amdgpu_waves_per_eu(2, 2)))
void k_scan(const unsigned int* __restrict__ Whp, const unsigned int* __restrict__ WS,
            const __half* __restrict__ G, float* __restrict__ hfin) {
  __shared__ __align__(16) unsigned int h2[2 * HBUFW];    // double-buffered h pairs

  const int t = threadIdx.x;
  const int b = blockIdx.x;
  const int kq = t & 3;
  const int cq = t >> 2;                 // 0..127
  const int c2 = 2 * cq;
  const int z = (int)(blockIdx.x >> 20); // always 0; opaque -> defeats LICM

  ROWS22(DEF_ROW)
  ROWS22(LD_ROW)

  if (t < 2 * HBUFW) h2[t] = 0u;   // zero both h buffers (incl. pads)

  // per-thread gate-x column (valid for kq 0/2 lanes): col = 2cq + (kq>>1)
  const __half* gp2 = G + (size_t)b * T_STEPS * 1024 + (c2 + (kq >> 1));
  const bool act_lane = (kq & 1) == 0;
  float gxi = 0.f, gxg = 0.f, gxf = 0.f, gxo = 0.f;
  if (act_lane) {
    gxi = __half2float(gp2[0]);   gxg = __half2float(gp2[256]);
    gxf = __half2float(gp2[512]); gxo = __half2float(gp2[768]);
  }
  float c_state = 0.0f;
  __syncthreads();

  const unsigned int* wsb = WS + t * 8;

  for (int step = 0; step < T_STEPS; ++step) {
    // pin resident weights EVERY iteration (defeats live-range split + reload)
    PIN_ROW2(0, 1)   PIN_ROW2(2, 3)   PIN_ROW2(4, 5)   PIN_ROW2(6, 7)
    PIN_ROW2(8, 9)   PIN_ROW2(10, 11) PIN_ROW2(12, 13) PIN_ROW2(14, 15)
    PIN_ROW2(16, 17) PIN_ROW2(18, 19) PIN_ROW2(20, 21)

    // prefetch next step's gate-x (consumed next iteration)
    float ni = 0.f, ng = 0.f, nf = 0.f, no = 0.f;
    {
      int nx = step + 1 < T_STEPS ? step + 1 : T_STEPS - 1;
      if (act_lane) {
        const __half* q = gp2 + (size_t)nx * 1024;
        ni = __half2float(q[0]);   ng = __half2float(q[256]);
        nf = __half2float(q[512]); no = __half2float(q[768]);
      }
    }

    const int rd = (step & 1) * HBUFW;
    const unsigned int* hr = h2 + rd + kq * 36;   // this quarter's h pairs (read buf)
    const unsigned int* wsp = wsb + z * step;     // stream base (anti-LICM)

    float acc0 = 0.f, acc1 = 0.f, acc2 = 0.f, acc3 = 0.f;
    float acc4 = 0.f, acc5 = 0.f, acc6 = 0.f, acc7 = 0.f;

    // stream h values (rows 22..31)
    u32x2 hs0 = *(const u32x2*)(hr + 22);
    u32x2 hs1 = *(const u32x2*)(hr + 24);
    u32x2 hs2 = *(const u32x2*)(hr + 26);
    u32x2 hs3 = *(const u32x2*)(hr + 28);
    u32x2 hs4 = *(const u32x2*)(hr + 30);

    // pulse 0+1 loads in flight, interleave with register dots
    SLOAD(0) SLOAD(1)
    DOT_PAIR(0, 1)   DOT_PAIR(2, 3)   DOT_PAIR(4, 5)   DOT_PAIR(6, 7)
    SDOT(0, hs0.x) SDOT(1, hs0.y)
    SLOAD(2) SLOAD(3)
    DOT_PAIR(8, 9)   DOT_PAIR(10, 11) DOT_PAIR(12, 13)
    SDOT(2, hs1.x) SDOT(3, hs1.y)
    SLOAD(4) SLOAD(5)
    DOT_PAIR(14, 15) DOT_PAIR(16, 17)
    SDOT(4, hs2.x) SDOT(5, hs2.y)
    SLOAD(6) SLOAD(7)
    DOT_PAIR(18, 19) DOT_PAIR(20, 21)
    SDOT(6, hs3.x) SDOT(7, hs3.y)
    SLOAD(8) SLOAD(9)
    SDOT(8, hs4.x) SDOT(9, hs4.y)

    // quad reduction over kq via DPP
#define QRED(a) { \
    int m1 = __builtin_amdgcn_update_dpp(0, __builtin_bit_cast(int, a), 0xB1, 0xF, 0xF, true); \
    a += __builtin_bit_cast(float, m1); \
    int m2 = __builtin_amdgcn_update_dpp(0, __builtin_bit_cast(int, a), 0x4E, 0xF, 0xF, true); \
    a += __builtin_bit_cast(float, m2); }
    QRED(acc0) QRED(acc1) QRED(acc2) QRED(acc3)
    QRED(acc4) QRED(acc5) QRED(acc6) QRED(acc7)
#undef QRED

    if (act_lane) {
      const int s = kq >> 1;   // which of the 2 cols this lane handles
      float gi = (s ? acc1 : acc0) + gxi;
      float gg = (s ? acc3 : acc2) + gxg;
      float gf = (s ? acc5 : acc4) + gxf;   // +1 folded in G
      float go = (s ? acc7 : acc6) + gxo;
      float si = 1.0f / (1.0f + __expf(-gi));
      float sf = 1.0f / (1.0f + __expf(-gf));
      float so = 1.0f / (1.0f + __expf(-go));
      float eg = __expf(2.0f * gg);
      float tg = 1.0f - 2.0f / (eg + 1.0f);
      c_state = sf * c_state + si * tg;
      float ec = __expf(2.0f * c_state);
      float tc = 1.0f - 2.0f / (ec + 1.0f);
      float h = so * tc;
      __half* hw = (__half*)(h2 + (HBUFW - rd));
      hw[(((cq >> 5) * 36) + (cq & 31)) * 2 + s] = __float2half_rn(h);
      if (step == T_STEPS - 1) hfin[b * 256 + c2 + s] = h;
    }
    gxi = ni; gxg = ng; gxf = nf; gxo = no;
    __syncthreads();
  }
}

// ---------------- head ----------------
__global__ void k_head(const float* __restrict__ hfin, const float* __restrict__ Wfc,
                       const float* __restrict__ bfc, const float* __restrict__ Wout,
                       const float* __restrict__ bout, float* __restrict__ out) {
  __shared__ float hs[256];
  __shared__ float fcs[256];
  int b = blockIdx.x, j = threadIdx.x;
  hs[j] = hfin[b * 256 + j];
  __syncthreads();
  float acc = bfc[j];
#pragma unroll 8
  for (int k = 0; k < 256; ++k) acc += hs[k] * Wfc[k * 256 + j];
  fcs[j] = acc;
  __syncthreads();
  if (j < 24) {
    float a2 = bout[j];
#pragma unroll 8
    for (int k = 0; k < 256; ++k) a2 += fcs[k] * Wout[k * 24 + j];
    out[b * 24 + j] = a2;
  }
}

extern "C" void kernel_launch(void* const* d_in, const int* in_sizes, int n_in,
                              void* d_out, int out_size, void* d_ws, size_t ws_size,
                              hipStream_t stream) {
  const float* x    = (const float*)d_in[0];
  const float* Wl   = (const float*)d_in[1];
  const float* bl   = (const float*)d_in[2];
  const float* Wfc  = (const float*)d_in[3];
  const float* bfc  = (const float*)d_in[4];
  const float* Wout = (const float*)d_in[5];
  const float* bout = (const float*)d_in[6];
  float* out = (float*)d_out;

  char* ws = (char*)d_ws;
  unsigned short* xbf = (unsigned short*)ws;                    //  67108864  x as bf16
  unsigned int*   WS  = (unsigned int*)ws;                      //    163840  stream tail (reuses dead xbf)
  unsigned short* WxT = (unsigned short*)(ws + 67108864);       //    524288  Wx^T bf16
  unsigned int*   Whp = (unsigned int*)(ws + 67633152);         //    524288  Wh f16 pairs [128][1024]
  __half*         G   = (__half*)(ws + 68157440);               // 268435456  gates_x f16 [B][T][1024]
  float*          hfin= (float*)(ws + 336592896);               //     32768  final h f32

  k_prep_x<<<32768, 256, 0, stream>>>((const float4*)x, xbf, 8388608);
  k_prep_w<<<1536, 256, 0, stream>>>(Wl, WxT, Whp);
  dim3 gx(2048, 16, 1);
  k_xproj<<<gx, 256, 0, stream>>>(xbf, WxT, bl, G);
  k_prep_ws<<<160, 256, 0, stream>>>(Whp, WS);   // after xproj: xbf region is dead
  k_scan<<<32, 512, 0, stream>>>(Whp, WS, G, hfin);
  k_head<<<32, 256, 0, stream>>>(hfin, Wfc, bfc, Wout, bout, out);
}